// Round 23
// baseline (112.157 us; speedup 1.0000x reference)
//
#include <hip/hip_runtime.h>
#include <hip/hip_bf16.h>
#include <stdint.h>

// Problem constants (from reference): B=32, NB=64, PL=20, FD=4096, H=1024
#define B_   32
#define NB_  64
#define PL_  20
#define FD_  4096
#define H_   1024
#define M_   (B_ * NB_)   // 2048 regions

typedef short bf16x8 __attribute__((ext_vector_type(8)));
typedef float f32x4  __attribute__((ext_vector_type(4)));

// f32 -> bf16 round-to-nearest-even
__device__ __forceinline__ ushort f2bf(float f) {
    uint32_t u = __builtin_bit_cast(uint32_t, f);
    u += 0x7fffu + ((u >> 16) & 1u);
    return (ushort)(u >> 16);
}

// ---------------------------------------------------------------------------
// Fused prep kernel (R16-verified structure; zero range now covers BOTH
// output maps since lang GEMM is split-K too):
//   blocks [0, 2048)     : pool language -> pooled bf16 (1 region/block)
//   blocks [2048, 4096)  : vision f32 -> bf16 (4 float4/thread)
//   blocks [4096, 6144)  : WvT: 2x (32x32) transpose tiles per block
//   blocks [6144, 6656)  : WlT: 2x (32x32) transpose tiles per block
//   blocks [6656, 7680)  : zero out[0..4M) floats = lang_map + vis_map (16 MB)
// ---------------------------------------------------------------------------
__global__ __launch_bounds__(256) void prep_kernel(
    const float* __restrict__ lang, const int* __restrict__ plen,
    ushort* __restrict__ pooled,
    const float* __restrict__ vision, ushort* __restrict__ visionb,
    const float* __restrict__ Wv, ushort* __restrict__ WvT,
    const float* __restrict__ Wl, ushort* __restrict__ WlT,
    float* __restrict__ out_zero)
{
    __shared__ float tile[32][33];   // transpose staging (+1 pad)
    int blk = blockIdx.x;
    int tid = threadIdx.x;

    if (blk < 2048) {
        // ---- pool: region r = blk ----
        int r = blk;
        int h = tid << 2;
        const float* base = lang + (size_t)r * (PL_ * H_) + h;
        float sx = 0.f, sy = 0.f, sz = 0.f, sw = 0.f;
#pragma unroll
        for (int p = 0; p < PL_; ++p) {
            float4 v = *(const float4*)(base + (size_t)p * H_);
            sx += v.x; sy += v.y; sz += v.z; sw += v.w;
        }
        float inv = 1.0f / (float)plen[r];
        ushort4 o = make_ushort4(f2bf(sx * inv), f2bf(sy * inv),
                                 f2bf(sz * inv), f2bf(sw * inv));
        *(ushort4*)(pooled + (size_t)r * H_ + h) = o;
    } else if (blk < 4096) {
        // ---- vision f32 -> bf16, 4 float4 per thread ----
        int base = (blk - 2048) * 1024 + tid;
#pragma unroll
        for (int it = 0; it < 4; ++it) {
            int i = base + it * 256;           // < 2048*4096/4
            float4 v = ((const float4*)vision)[i];
            ushort4 o = make_ushort4(f2bf(v.x), f2bf(v.y), f2bf(v.z), f2bf(v.w));
            ((ushort4*)visionb)[i] = o;
        }
    } else if (blk < 6656) {
        // ---- W transpose: 2 tiles per block ----
        const float* W; ushort* Wt; int K, b0;
        if (blk < 6144) { W = Wv; Wt = WvT; K = FD_; b0 = (blk - 4096) * 2; }
        else            { W = Wl; Wt = WlT; K = H_;  b0 = (blk - 6144) * 2; }
        int tx = tid & 31, ty = tid >> 5;      // ty in 0..7
#pragma unroll
        for (int t = 0; t < 2; ++t) {
            int b = b0 + t;
            int n0 = (b & 31) * 32, k0 = (b >> 5) * 32;
#pragma unroll
            for (int i = 0; i < 32; i += 8)
                tile[ty + i][tx] = W[(size_t)(k0 + ty + i) * H_ + n0 + tx];
            __syncthreads();
#pragma unroll
            for (int i = 0; i < 32; i += 8)
                Wt[(size_t)(n0 + ty + i) * K + k0 + tx] = f2bf(tile[tx][ty + i]);
            __syncthreads();               // safe LDS reuse for tile 2
        }
    } else {
        // ---- zero both output maps: 4 float4/thread, 1024 blocks = 16 MB ----
        int base = (blk - 6656) * 1024 + tid;
#pragma unroll
        for (int it = 0; it < 4; ++it)
            ((float4*)out_zero)[base + it * 256] =
                make_float4(0.f, 0.f, 0.f, 0.f);
    }
}

// ---------------------------------------------------------------------------
// Dual bf16 GEMM-BT — 256x256 TILE (2x arithmetic intensity), R10 schedule:
// CHANGE vs R19 (single variable = tile geometry): BM=BN=256, BK=64; 8 waves
// (2x4), per-wave 128x64 = acc[8][4]; LDS 128 KB -> 1 block/CU; grid 256.
// Rationale: 4 orthogonal nulls (T5/unpin/dispatch/occupancy) all left
// staging-traffic-per-FLOP unchanged (64 FLOP/B). 256^2 doubles intensity to
// 128 FLOP/B (vision L2/L3 traffic 256->128 MB). m230-V0 measured 682 TF for
// exactly this geometry+schedule family (2ph counted-vmcnt, 1 blk/CU).
//   wgid [0,192)   : vision GEMM (K=4096, 64 BK-steps) split-K 6-way
//                    {11,11,11,11,10,10}; tiles x=w>>2 (0..7), y=w&3 (0..3).
//   wgid [192,256) : lang GEMM (K=1024, 16 steps) split-K 2-way {8,8}.
// All epilogues atomicAdd into pre-zeroed out (bias on ks==0).
// Pipeline per K-step (R10-proven): vmcnt(8) [last: 0] -> s_barrier ->
//   ds_read frags -> MFMA (compiler-interleaved lgkmcnt) -> s_barrier ->
//   stage(kt+2).  8 gload_lds issues/tile/thread -> steady vmcnt(8).
// Swizzle (rule 21): linear LDS dest, source col ^= ((row&7)<<4); read rows
// = {wr*128,wc*64} + m*16 + lx === lx (mod 8) -> same XOR on read side.
// __launch_bounds__(512,2): 2 waves/SIMD -> 256 VGPR budget (acc 128 + frags).
// ---------------------------------------------------------------------------
#define BM 256
#define BN 256
#define BK 64

__device__ __forceinline__ void async16(const void* g, void* l) {
    __builtin_amdgcn_global_load_lds(
        (const __attribute__((address_space(1))) void*)g,
        (__attribute__((address_space(3))) void*)l, 16, 0, 0);
}

// Stage one 256x64 A-tile (32 KB) + 256x64 B-tile (32 KB), bf16.
// 512 threads x 16B x 4 issues per matrix (8 loads/thread/tile).
__device__ __forceinline__ void stage_tile(
    const char* Ag, const char* Bg, size_t Kb, size_t ko,
    char* AsB, char* BsB, int tid)
{
#pragma unroll
    for (int j = 0; j < 4; ++j) {
        int off = j * 8192 + tid * 16;                  // linear LDS byte off
        int row = off >> 7;                             // 128 B per row, 0..255
        int cbl = off & 127;                            // LDS byte col
        int cbg = cbl ^ ((row & 7) << 4);               // swizzled global col
        async16(Ag + (size_t)row * Kb + ko + cbg, AsB + off);
        async16(Bg + (size_t)row * Kb + ko + cbg, BsB + off);
    }
}

__global__ __launch_bounds__(512, 2) void gemm_bt_dual(
    const ushort* __restrict__ A1, const ushort* __restrict__ Bt1,
    const float* __restrict__ bias1, float* __restrict__ C1,
    const ushort* __restrict__ A2, const ushort* __restrict__ Bt2,
    const float* __restrict__ bias2, float* __restrict__ C2)
{
    __shared__ ushort As[2][BM * BK];   // 2 x 32 KB
    __shared__ ushort Bs[2][BN * BK];   // 2 x 32 KB   (total 128 KB)

    int wg = blockIdx.x;
    bool isV = wg < 192;
    int w, ks, nk, k0s;
    if (isV) {
        ks = wg >> 5;                   // 0..5
        w  = wg & 31;                   // 32 tiles: x=w>>2 (0..7), y=w&3
        nk  = (ks < 4) ? 11 : 10;       // 11*4 + 10*2 = 64 K-steps
        k0s = (ks < 4) ? ks * 11 : 44 + (ks - 4) * 10;
    } else {
        int v = wg - 192;
        ks = v >> 5;                    // 0..1
        w  = v & 31;
        nk = 8; k0s = ks * 8;           // 8+8 = 16 K-steps
    }
    int y = w & 3, x = w >> 2;

    const ushort* A   = isV ? A1 : A2;
    const ushort* Bt  = isV ? Bt1 : Bt2;
    const float* bias = isV ? bias1 : bias2;
    float* C          = isV ? C1 : C2;
    int K             = isV ? FD_ : H_;

    const int N = H_;
    int tid  = threadIdx.x;
    int wave = tid >> 6, lane = tid & 63;
    int lx = lane & 15, lz = lane >> 4;
    int wr = wave >> 2, wc = wave & 3;  // 2x4 waves, each owns 128x64
    int row0 = x * BM;
    int col0 = y * BN;

    size_t Kb = (size_t)K * 2;          // bytes per logical row

    const char* Ag = (const char*)A  + (size_t)row0 * Kb;
    const char* Bg = (const char*)Bt + (size_t)col0 * Kb;

    int sw = (lx & 7) << 4;             // read-side swizzle XOR

    f32x4 acc[8][4] = {};

    // prologue: stage tiles 0,1 (16 outstanding loads per thread)
    stage_tile(Ag, Bg, Kb, (size_t)k0s * 128,       (char*)As[0], (char*)Bs[0], tid);
    stage_tile(Ag, Bg, Kb, (size_t)(k0s + 1) * 128, (char*)As[1], (char*)Bs[1], tid);

    for (int kt = 0; kt < nk; ++kt) {
        // FIFO: outstanding = {kt:8, kt+1:8}; vmcnt(8) == tile kt landed
        if (kt < nk - 1) asm volatile("s_waitcnt vmcnt(8)" ::: "memory");
        else             asm volatile("s_waitcnt vmcnt(0)" ::: "memory");
        __builtin_amdgcn_s_barrier();   // all waves' stage(kt) visible

        const char* Ab = (const char*)As[kt & 1];
        const char* Bb = (const char*)Bs[kt & 1];
#pragma unroll
        for (int kk = 0; kk < 2; ++kk) {
            bf16x8 af[8], bfr[4];
#pragma unroll
            for (int m = 0; m < 8; ++m)
                af[m] = *(const bf16x8*)(Ab +
                    (wr * 128 + m * 16 + lx) * 128 + ((kk * 64 + lz * 16) ^ sw));
#pragma unroll
            for (int n = 0; n < 4; ++n)
                bfr[n] = *(const bf16x8*)(Bb +
                    (wc * 64 + n * 16 + lx) * 128 + ((kk * 64 + lz * 16) ^ sw));
            // no lgkmcnt pin: compiler staggers lgkmcnt(N) before MFMAs
#pragma unroll
            for (int m = 0; m < 8; ++m)
#pragma unroll
                for (int n = 0; n < 4; ++n)
                    acc[m][n] = __builtin_amdgcn_mfma_f32_16x16x32_bf16(
                        af[m], bfr[n], acc[m][n], 0, 0, 0);
        }

        __builtin_amdgcn_s_barrier();   // buf[kt&1] dead block-wide
        if (kt + 2 < nk)
            stage_tile(Ag, Bg, Kb, (size_t)(k0s + kt + 2) * 128,
                       (char*)As[kt & 1], (char*)Bs[kt & 1], tid);
    }

    // Epilogue: atomicAdd partials (out pre-zeroed in prep); bias on ks==0.
    // D frag: col = lane&15, row = (lane>>4)*4 + reg  [verified map]
#pragma unroll
    for (int m = 0; m < 8; ++m) {
        int row = row0 + wr * 128 + m * 16 + lz * 4;
#pragma unroll
        for (int n = 0; n < 4; ++n) {
            int col = col0 + wc * 64 + n * 16 + lx;
            float bb = (ks == 0) ? bias[col] : 0.f;
#pragma unroll
            for (int r = 0; r < 4; ++r)
                atomicAdd(&C[(size_t)(row + r) * N + col],
                          acc[m][n][r] + bb);
        }
    }
}

// ---------------------------------------------------------------------------
extern "C" void kernel_launch(void* const* d_in, const int* in_sizes, int n_in,
                              void* d_out, int out_size, void* d_ws, size_t ws_size,
                              hipStream_t stream) {
    const float* vision   = (const float*)d_in[0];   // [2048, 4096]
    const float* language = (const float*)d_in[1];   // [2048, 20, 1024]
    const int*   plen     = (const int*)d_in[2];     // [2048]
    const float* Wv       = (const float*)d_in[3];   // [4096, 1024]
    const float* bv       = (const float*)d_in[4];   // [1024]
    const float* Wl       = (const float*)d_in[5];   // [1024, 1024]
    const float* bl       = (const float*)d_in[6];   // [1024]

    float* out      = (float*)d_out;
    float* lang_map = out;                        // output 0: [2048,1024]
    float* vis_map  = out + (size_t)M_ * H_;      // output 1: [2048,1024]

    char* ws = (char*)d_ws;
    ushort* pooled  = (ushort*)(ws);                   // 4 MB  [2048][1024]
    ushort* visionb = (ushort*)(ws + (4u  << 20));     // 16 MB [2048][4096]
    ushort* WvT     = (ushort*)(ws + (20u << 20));     // 8 MB  [1024][4096]
    ushort* WlT     = (ushort*)(ws + (28u << 20));     // 2 MB  [1024][1024]

    // prep: 2048 pool + 2048 cvt + 2048 WvT + 512 WlT + 1024 zero = 7680
    hipLaunchKernelGGL(prep_kernel, dim3(7680), dim3(256), 0, stream,
                       language, plen, pooled, vision, visionb,
                       Wv, WvT, Wl, WlT, out);
    // GEMM: 256 blocks x 512 threads (192 vision split-K6 + 64 lang split-K2)
    hipLaunchKernelGGL(gemm_bt_dual, dim3(256), dim3(512), 0, stream,
                       visionb, WvT, bv, vis_map,
                       pooled,  WlT, bl, lang_map);
}

// Round 24
// 103.274 us; speedup vs baseline: 1.0860x; 1.0860x over previous
//
#include <hip/hip_runtime.h>
#include <hip/hip_bf16.h>
#include <stdint.h>

// Problem constants (from reference): B=32, NB=64, PL=20, FD=4096, H=1024
#define B_   32
#define NB_  64
#define PL_  20
#define FD_  4096
#define H_   1024
#define M_   (B_ * NB_)   // 2048 regions

typedef short bf16x8 __attribute__((ext_vector_type(8)));
typedef float f32x4  __attribute__((ext_vector_type(4)));

// f32 -> bf16 round-to-nearest-even
__device__ __forceinline__ ushort f2bf(float f) {
    uint32_t u = __builtin_bit_cast(uint32_t, f);
    u += 0x7fffu + ((u >> 16) & 1u);
    return (ushort)(u >> 16);
}

// ---------------------------------------------------------------------------
// Fused prep kernel (R16-verified, at BW floor ~37 us; byte-identical):
//   blocks [0, 2048)     : pool language -> pooled bf16 (1 region, 80 KB rd)
//   blocks [2048, 4096)  : vision f32 -> bf16 (4 float4/thread)
//   blocks [4096, 6144)  : WvT: 2x (32x32) transpose tiles per block
//   blocks [6144, 6656)  : WlT: 2x (32x32) transpose tiles per block
//   blocks [6656, 7168)  : zero vis_map (4 float4/thread, 8 MB)
// ---------------------------------------------------------------------------
__global__ __launch_bounds__(256) void prep_kernel(
    const float* __restrict__ lang, const int* __restrict__ plen,
    ushort* __restrict__ pooled,
    const float* __restrict__ vision, ushort* __restrict__ visionb,
    const float* __restrict__ Wv, ushort* __restrict__ WvT,
    const float* __restrict__ Wl, ushort* __restrict__ WlT,
    float* __restrict__ vis_zero)
{
    __shared__ float tile[32][33];   // transpose staging (+1 pad)
    int blk = blockIdx.x;
    int tid = threadIdx.x;

    if (blk < 2048) {
        // ---- pool: region r = blk ----
        int r = blk;
        int h = tid << 2;
        const float* base = lang + (size_t)r * (PL_ * H_) + h;
        float sx = 0.f, sy = 0.f, sz = 0.f, sw = 0.f;
#pragma unroll
        for (int p = 0; p < PL_; ++p) {
            float4 v = *(const float4*)(base + (size_t)p * H_);
            sx += v.x; sy += v.y; sz += v.z; sw += v.w;
        }
        float inv = 1.0f / (float)plen[r];
        ushort4 o = make_ushort4(f2bf(sx * inv), f2bf(sy * inv),
                                 f2bf(sz * inv), f2bf(sw * inv));
        *(ushort4*)(pooled + (size_t)r * H_ + h) = o;
    } else if (blk < 4096) {
        // ---- vision f32 -> bf16, 4 float4 per thread ----
        int base = (blk - 2048) * 1024 + tid;
#pragma unroll
        for (int it = 0; it < 4; ++it) {
            int i = base + it * 256;           // < 2048*4096/4
            float4 v = ((const float4*)vision)[i];
            ushort4 o = make_ushort4(f2bf(v.x), f2bf(v.y), f2bf(v.z), f2bf(v.w));
            ((ushort4*)visionb)[i] = o;
        }
    } else if (blk < 6656) {
        // ---- W transpose: 2 tiles per block ----
        const float* W; ushort* Wt; int K, b0;
        if (blk < 6144) { W = Wv; Wt = WvT; K = FD_; b0 = (blk - 4096) * 2; }
        else            { W = Wl; Wt = WlT; K = H_;  b0 = (blk - 6144) * 2; }
        int tx = tid & 31, ty = tid >> 5;      // ty in 0..7
#pragma unroll
        for (int t = 0; t < 2; ++t) {
            int b = b0 + t;
            int n0 = (b & 31) * 32, k0 = (b >> 5) * 32;
#pragma unroll
            for (int i = 0; i < 32; i += 8)
                tile[ty + i][tx] = W[(size_t)(k0 + ty + i) * H_ + n0 + tx];
            __syncthreads();
#pragma unroll
            for (int i = 0; i < 32; i += 8)
                Wt[(size_t)(n0 + ty + i) * K + k0 + tx] = f2bf(tile[tx][ty + i]);
            __syncthreads();               // safe LDS reuse for tile 2
        }
    } else {
        // ---- zero vis_map: 4 float4 per thread (8 MB total) ----
        int base = (blk - 6656) * 1024 + tid;
#pragma unroll
        for (int it = 0; it < 4; ++it)
            ((float4*)vis_zero)[base + it * 256] =
                make_float4(0.f, 0.f, 0.f, 0.f);
    }
}

// ---------------------------------------------------------------------------
// Dual bf16 GEMM-BT — R16-proven core (measured best 87.16 us), with ONE
// change: UNIFORM 16-step blocks for perfect packing at 2 blocks/CU.
//   wgid [0,512)   : vision GEMM (K=4096) split-K 4-way {16,16,16,16};
//                    atomicAdd partials (vis_map pre-zeroed); bias on ks==0.
//   wgid [512,640) : language GEMM (K=1024, 16 steps), plain stores + bias.
// All 640 blocks = exactly 16 K-steps -> no mixed-length tail (R16 wasted
// ~3-4 us when 16-step lang blocks retired before 21/22-step vision blocks).
// 640 blocks / 256 CUs at 2-resident: uniform drain, 2.5 rounds.
// Schedule (R10/R16-proven, unchanged): per K-step vmcnt(8) [last: 0] ->
//   s_barrier -> ds_read frags -> lgkmcnt(0) -> s_barrier -> stage(kt+2) ->
//   setprio(1) 32 MFMA setprio(0).
// BM=BN=128, BK=64, 256 thr (4 waves 2x2, per-wave 64x64 = acc[4][4]).
// Swizzle (rule 21): linear LDS dest, source col ^= ((row&7)<<4), read col
// applies the same XOR. XCD pinning: wg%8 == y (all ranges) -> B-panel
// L2-resident per XCD.
// ---------------------------------------------------------------------------
#define BM 128
#define BN 128
#define BK 64

__device__ __forceinline__ void async16(const void* g, void* l) {
    __builtin_amdgcn_global_load_lds(
        (const __attribute__((address_space(1))) void*)g,
        (__attribute__((address_space(3))) void*)l, 16, 0, 0);
}

// Stage one 128x64 A-tile (16 KB) + 128x64 B-tile (16 KB), bf16.
// 256 threads x 16B x 4 issues per matrix (8 loads/thread/tile).
__device__ __forceinline__ void stage_tile(
    const char* Ag, const char* Bg, size_t Kb, size_t ko,
    char* AsB, char* BsB, int tid)
{
#pragma unroll
    for (int j = 0; j < 4; ++j) {
        int off = j * 4096 + tid * 16;                  // linear LDS byte off
        int row = off >> 7;                             // 128 B per row
        int cbl = off & 127;                            // LDS byte col
        int cbg = cbl ^ ((row & 7) << 4);               // swizzled global col
        async16(Ag + (size_t)row * Kb + ko + cbg, AsB + off);
        async16(Bg + (size_t)row * Kb + ko + cbg, BsB + off);
    }
}

__global__ __launch_bounds__(256) void gemm_bt_dual(
    const ushort* __restrict__ A1, const ushort* __restrict__ Bt1,
    const float* __restrict__ bias1, float* __restrict__ C1,
    const ushort* __restrict__ A2, const ushort* __restrict__ Bt2,
    const float* __restrict__ bias2, float* __restrict__ C2)
{
    __shared__ ushort As[2][BM * BK];   // 2 x 16 KB
    __shared__ ushort Bs[2][BN * BK];   // 2 x 16 KB

    int wg = blockIdx.x;
    bool isV = wg < 512;
    int w, ks;
    if (isV) {
        ks = wg >> 7;                   // 0..3 (split-K 4-way, 16 steps each)
        w  = wg & 127;
    } else {
        ks = 0; w = wg - 512;           // lang: 16 steps, full K
    }
    const int nk  = 16;
    int k0s = isV ? (ks << 4) : 0;
    int y = w & 7, x = w >> 3;          // XCD == wg%8 == y (round-robin)

    const ushort* A   = isV ? A1 : A2;
    const ushort* Bt  = isV ? Bt1 : Bt2;
    const float* bias = isV ? bias1 : bias2;
    float* C          = isV ? C1 : C2;
    int K             = isV ? FD_ : H_;

    const int N = H_;
    int tid  = threadIdx.x;
    int wave = tid >> 6, lane = tid & 63;
    int lx = lane & 15, lz = lane >> 4;
    int wr = wave >> 1, wc = wave & 1;  // 2x2 waves, each owns 64x64
    int row0 = x * BM;
    int col0 = y * BN;

    size_t Kb = (size_t)K * 2;          // bytes per logical row

    const char* Ag = (const char*)A  + (size_t)row0 * Kb;
    const char* Bg = (const char*)Bt + (size_t)col0 * Kb;

    int sw = (lx & 7) << 4;             // read-side swizzle XOR

    f32x4 acc[4][4] = {};

    // prologue: stage tiles 0,1 (16 outstanding loads per thread)
    stage_tile(Ag, Bg, Kb, (size_t)k0s * 128,       (char*)As[0], (char*)Bs[0], tid);
    stage_tile(Ag, Bg, Kb, (size_t)(k0s + 1) * 128, (char*)As[1], (char*)Bs[1], tid);

    for (int kt = 0; kt < nk; ++kt) {
        if (kt < nk - 1) asm volatile("s_waitcnt vmcnt(8)" ::: "memory");
        else             asm volatile("s_waitcnt vmcnt(0)" ::: "memory");
        __builtin_amdgcn_s_barrier();   // all waves' stage(kt) visible

        const char* Ab = (const char*)As[kt & 1];
        const char* Bb = (const char*)Bs[kt & 1];
        bf16x8 af[2][4], bfr[2][4];
#pragma unroll
        for (int kk = 0; kk < 2; ++kk) {
#pragma unroll
            for (int m = 0; m < 4; ++m)
                af[kk][m] = *(const bf16x8*)(Ab +
                    (wr * 64 + m * 16 + lx) * 128 + ((kk * 64 + lz * 16) ^ sw));
#pragma unroll
            for (int n = 0; n < 4; ++n)
                bfr[kk][n] = *(const bf16x8*)(Bb +
                    (wc * 64 + n * 16 + lx) * 128 + ((kk * 64 + lz * 16) ^ sw));
        }
        asm volatile("s_waitcnt lgkmcnt(0)" ::: "memory"); // reads complete
        __builtin_amdgcn_s_barrier();   // buffer kt now reusable block-wide

        if (kt + 2 < nk)
            stage_tile(Ag, Bg, Kb, (size_t)(k0s + kt + 2) * 128,
                       (char*)As[kt & 1], (char*)Bs[kt & 1], tid);

        __builtin_amdgcn_s_setprio(1);  // T5 (R16 config, measured best-equal)
#pragma unroll
        for (int kk = 0; kk < 2; ++kk)
#pragma unroll
            for (int m = 0; m < 4; ++m)
#pragma unroll
                for (int n = 0; n < 4; ++n)
                    acc[m][n] = __builtin_amdgcn_mfma_f32_16x16x32_bf16(
                        af[kk][m], bfr[kk][n], acc[m][n], 0, 0, 0);
        __builtin_amdgcn_s_setprio(0);
    }

    // Epilogue. D frag: col = lane&15, row = (lane>>4)*4 + reg  [verified map]
#pragma unroll
    for (int m = 0; m < 4; ++m) {
        int row = row0 + wr * 64 + m * 16 + lz * 4;
#pragma unroll
        for (int n = 0; n < 4; ++n) {
            int col = col0 + wc * 64 + n * 16 + lx;
            float bb = (ks == 0) ? bias[col] : 0.f;
            if (isV) {
#pragma unroll
                for (int r = 0; r < 4; ++r)
                    atomicAdd(&C[(size_t)(row + r) * N + col],
                              acc[m][n][r] + bb);
            } else {
#pragma unroll
                for (int r = 0; r < 4; ++r)
                    C[(size_t)(row + r) * N + col] = acc[m][n][r] + bb;
            }
        }
    }
}

// ---------------------------------------------------------------------------
extern "C" void kernel_launch(void* const* d_in, const int* in_sizes, int n_in,
                              void* d_out, int out_size, void* d_ws, size_t ws_size,
                              hipStream_t stream) {
    const float* vision   = (const float*)d_in[0];   // [2048, 4096]
    const float* language = (const float*)d_in[1];   // [2048, 20, 1024]
    const int*   plen     = (const int*)d_in[2];     // [2048]
    const float* Wv       = (const float*)d_in[3];   // [4096, 1024]
    const float* bv       = (const float*)d_in[4];   // [1024]
    const float* Wl       = (const float*)d_in[5];   // [1024, 1024]
    const float* bl       = (const float*)d_in[6];   // [1024]

    float* out      = (float*)d_out;
    float* lang_map = out;                        // output 0: [2048,1024]
    float* vis_map  = out + (size_t)M_ * H_;      // output 1: [2048,1024]

    char* ws = (char*)d_ws;
    ushort* pooled  = (ushort*)(ws);                   // 4 MB  [2048][1024]
    ushort* visionb = (ushort*)(ws + (4u  << 20));     // 16 MB [2048][4096]
    ushort* WvT     = (ushort*)(ws + (20u << 20));     // 8 MB  [1024][4096]
    ushort* WlT     = (ushort*)(ws + (28u << 20));     // 2 MB  [1024][1024]

    // prep: 2048 pool + 2048 cvt + 2048 WvT + 512 WlT + 512 zero = 7168
    hipLaunchKernelGGL(prep_kernel, dim3(7168), dim3(256), 0, stream,
                       language, plen, pooled, vision, visionb,
                       Wv, WvT, Wl, WlT, vis_map);
    // GEMM: 640 blocks x 256 threads (512 vision split-K4 + 128 language),
    // every block exactly 16 K-steps.
    hipLaunchKernelGGL(gemm_bt_dual, dim3(640), dim3(256), 0, stream,
                       visionb, WvT, bv, vis_map,
                       pooled,  WlT, bl, lang_map);
}

// Round 25
// 87.108 us; speedup vs baseline: 1.2876x; 1.1856x over previous
//
#include <hip/hip_runtime.h>
#include <hip/hip_bf16.h>
#include <stdint.h>

// Problem constants (from reference): B=32, NB=64, PL=20, FD=4096, H=1024
#define B_   32
#define NB_  64
#define PL_  20
#define FD_  4096
#define H_   1024
#define M_   (B_ * NB_)   // 2048 regions

typedef short bf16x8 __attribute__((ext_vector_type(8)));
typedef float f32x4  __attribute__((ext_vector_type(4)));

// f32 -> bf16 round-to-nearest-even
__device__ __forceinline__ ushort f2bf(float f) {
    uint32_t u = __builtin_bit_cast(uint32_t, f);
    u += 0x7fffu + ((u >> 16) & 1u);
    return (ushort)(u >> 16);
}

// ---------------------------------------------------------------------------
// Fused prep kernel (R16-measured, at BW floor ~37 us):
//   blocks [0, 2048)     : pool language -> pooled bf16 (1 region, 80 KB rd)
//   blocks [2048, 4096)  : vision f32 -> bf16 (4 float4/thread)
//   blocks [4096, 6144)  : WvT: 2x (32x32) transpose tiles per block
//   blocks [6144, 6656)  : WlT: 2x (32x32) transpose tiles per block
//   blocks [6656, 7168)  : zero vis_map (4 float4/thread, 8 MB)
// ---------------------------------------------------------------------------
__global__ __launch_bounds__(256) void prep_kernel(
    const float* __restrict__ lang, const int* __restrict__ plen,
    ushort* __restrict__ pooled,
    const float* __restrict__ vision, ushort* __restrict__ visionb,
    const float* __restrict__ Wv, ushort* __restrict__ WvT,
    const float* __restrict__ Wl, ushort* __restrict__ WlT,
    float* __restrict__ vis_zero)
{
    __shared__ float tile[32][33];   // transpose staging (+1 pad)
    int blk = blockIdx.x;
    int tid = threadIdx.x;

    if (blk < 2048) {
        // ---- pool: region r = blk ----
        int r = blk;
        int h = tid << 2;
        const float* base = lang + (size_t)r * (PL_ * H_) + h;
        float sx = 0.f, sy = 0.f, sz = 0.f, sw = 0.f;
#pragma unroll
        for (int p = 0; p < PL_; ++p) {
            float4 v = *(const float4*)(base + (size_t)p * H_);
            sx += v.x; sy += v.y; sz += v.z; sw += v.w;
        }
        float inv = 1.0f / (float)plen[r];
        ushort4 o = make_ushort4(f2bf(sx * inv), f2bf(sy * inv),
                                 f2bf(sz * inv), f2bf(sw * inv));
        *(ushort4*)(pooled + (size_t)r * H_ + h) = o;
    } else if (blk < 4096) {
        // ---- vision f32 -> bf16, 4 float4 per thread ----
        int base = (blk - 2048) * 1024 + tid;
#pragma unroll
        for (int it = 0; it < 4; ++it) {
            int i = base + it * 256;           // < 2048*4096/4
            float4 v = ((const float4*)vision)[i];
            ushort4 o = make_ushort4(f2bf(v.x), f2bf(v.y), f2bf(v.z), f2bf(v.w));
            ((ushort4*)visionb)[i] = o;
        }
    } else if (blk < 6656) {
        // ---- W transpose: 2 tiles per block ----
        const float* W; ushort* Wt; int K, b0;
        if (blk < 6144) { W = Wv; Wt = WvT; K = FD_; b0 = (blk - 4096) * 2; }
        else            { W = Wl; Wt = WlT; K = H_;  b0 = (blk - 6144) * 2; }
        int tx = tid & 31, ty = tid >> 5;      // ty in 0..7
#pragma unroll
        for (int t = 0; t < 2; ++t) {
            int b = b0 + t;
            int n0 = (b & 31) * 32, k0 = (b >> 5) * 32;
#pragma unroll
            for (int i = 0; i < 32; i += 8)
                tile[ty + i][tx] = W[(size_t)(k0 + ty + i) * H_ + n0 + tx];
            __syncthreads();
#pragma unroll
            for (int i = 0; i < 32; i += 8)
                Wt[(size_t)(n0 + ty + i) * K + k0 + tx] = f2bf(tile[tx][ty + i]);
            __syncthreads();               // safe LDS reuse for tile 2
        }
    } else {
        // ---- zero vis_map: 4 float4 per thread (8 MB total) ----
        int base = (blk - 6656) * 1024 + tid;
#pragma unroll
        for (int it = 0; it < 4; ++it)
            ((float4*)vis_zero)[base + it * 256] =
                make_float4(0.f, 0.f, 0.f, 0.f);
    }
}

// ---------------------------------------------------------------------------
// Dual bf16 GEMM-BT, split-K vision, 2 blocks/CU, counted vmcnt + T2 swizzle
// (R16-measured best: 87.16 us) + T5 setprio around the MFMA cluster:
//   C[M][N] = A[M][K] * Bt[N][K]^T (+ bias)
// Grid: 512 blocks x 256 threads (4 waves 2x2, per-wave 64x64 = acc[4][4]).
//   wgid [0,384)  : vision GEMM (K=4096) split-K 3-way {22,21,21};
//                   partials via atomicAdd (C pre-zeroed in prep);
//                   bias added by split ks==0.
//   wgid [384,512): language GEMM (K=1024, 16 steps), plain stores + bias.
// 512 blocks == 2/CU co-residency EXACTLY (R24 lesson: grid > 2xCU adds a
// ragged serialization round; co-residency binds harder than load balance).
// Pipeline: iter kt: vmcnt(8) [last: 0] -> barrier -> ds_read frags ->
//   lgkmcnt(0) -> barrier -> stage(kt+2) -> setprio(1) 32 MFMA setprio(0).
// Swizzle (rule 21): linear LDS dest, source col ^= ((row&7)<<4), read col
// applies the same XOR. XCD pinning: wg%8 == y -> B-panel L2-resident/XCD.
// ---------------------------------------------------------------------------
#define BM 128
#define BN 128
#define BK 64

__device__ __forceinline__ void async16(const void* g, void* l) {
    __builtin_amdgcn_global_load_lds(
        (const __attribute__((address_space(1))) void*)g,
        (__attribute__((address_space(3))) void*)l, 16, 0, 0);
}

// Stage one 128x64 A-tile (16 KB) + 128x64 B-tile (16 KB), bf16.
// 256 threads x 16B x 4 issues per matrix (8 loads/thread/tile).
__device__ __forceinline__ void stage_tile(
    const char* Ag, const char* Bg, size_t Kb, size_t ko,
    char* AsB, char* BsB, int tid)
{
#pragma unroll
    for (int j = 0; j < 4; ++j) {
        int off = j * 4096 + tid * 16;                  // linear LDS byte off
        int row = off >> 7;                             // 128 B per row
        int cbl = off & 127;                            // LDS byte col
        int cbg = cbl ^ ((row & 7) << 4);               // swizzled global col
        async16(Ag + (size_t)row * Kb + ko + cbg, AsB + off);
        async16(Bg + (size_t)row * Kb + ko + cbg, BsB + off);
    }
}

__global__ __launch_bounds__(256) void gemm_bt_dual(
    const ushort* __restrict__ A1, const ushort* __restrict__ Bt1,
    const float* __restrict__ bias1, float* __restrict__ C1,
    const ushort* __restrict__ A2, const ushort* __restrict__ Bt2,
    const float* __restrict__ bias2, float* __restrict__ C2)
{
    __shared__ ushort As[2][BM * BK];   // 2 x 16 KB
    __shared__ ushort Bs[2][BN * BK];   // 2 x 16 KB

    int wg = blockIdx.x;
    bool isV = wg < 384;
    int w, ks, nk, k0s;
    if (isV) {
        ks = wg >> 7;                   // 0..2
        w  = wg & 127;
        nk  = (ks == 0) ? 22 : 21;      // 22+21+21 = 64 K-steps
        k0s = (ks == 0) ? 0 : (22 + (ks - 1) * 21);
    } else {
        ks = 0; w = wg - 384; nk = 16; k0s = 0;
    }
    int y = w & 7, x = w >> 3;          // XCD == wg%8 == y (round-robin)

    const ushort* A   = isV ? A1 : A2;
    const ushort* Bt  = isV ? Bt1 : Bt2;
    const float* bias = isV ? bias1 : bias2;
    float* C          = isV ? C1 : C2;
    int K             = isV ? FD_ : H_;

    const int N = H_;
    int tid  = threadIdx.x;
    int wave = tid >> 6, lane = tid & 63;
    int lx = lane & 15, lz = lane >> 4;
    int wr = wave >> 1, wc = wave & 1;  // 2x2 waves, each owns 64x64
    int row0 = x * BM;
    int col0 = y * BN;

    size_t Kb = (size_t)K * 2;          // bytes per logical row

    const char* Ag = (const char*)A  + (size_t)row0 * Kb;
    const char* Bg = (const char*)Bt + (size_t)col0 * Kb;

    int sw = (lx & 7) << 4;             // read-side swizzle XOR

    f32x4 acc[4][4] = {};

    // prologue: stage tiles 0,1 (16 outstanding loads per thread)
    stage_tile(Ag, Bg, Kb, (size_t)k0s * 128,       (char*)As[0], (char*)Bs[0], tid);
    stage_tile(Ag, Bg, Kb, (size_t)(k0s + 1) * 128, (char*)As[1], (char*)Bs[1], tid);

    for (int kt = 0; kt < nk; ++kt) {
        if (kt < nk - 1) asm volatile("s_waitcnt vmcnt(8)" ::: "memory");
        else             asm volatile("s_waitcnt vmcnt(0)" ::: "memory");
        __builtin_amdgcn_s_barrier();   // all waves' stage(kt) visible

        const char* Ab = (const char*)As[kt & 1];
        const char* Bb = (const char*)Bs[kt & 1];
        bf16x8 af[2][4], bfr[2][4];
#pragma unroll
        for (int kk = 0; kk < 2; ++kk) {
#pragma unroll
            for (int m = 0; m < 4; ++m)
                af[kk][m] = *(const bf16x8*)(Ab +
                    (wr * 64 + m * 16 + lx) * 128 + ((kk * 64 + lz * 16) ^ sw));
#pragma unroll
            for (int n = 0; n < 4; ++n)
                bfr[kk][n] = *(const bf16x8*)(Bb +
                    (wc * 64 + n * 16 + lx) * 128 + ((kk * 64 + lz * 16) ^ sw));
        }
        asm volatile("s_waitcnt lgkmcnt(0)" ::: "memory"); // reads complete
        __builtin_amdgcn_s_barrier();   // buffer kt now reusable block-wide

        if (kt + 2 < nk)
            stage_tile(Ag, Bg, Kb, (size_t)(k0s + kt + 2) * 128,
                       (char*)As[kt & 1], (char*)Bs[kt & 1], tid);

        __builtin_amdgcn_s_setprio(1);  // T5: favor MFMA-issuing waves
#pragma unroll
        for (int kk = 0; kk < 2; ++kk)
#pragma unroll
            for (int m = 0; m < 4; ++m)
#pragma unroll
                for (int n = 0; n < 4; ++n)
                    acc[m][n] = __builtin_amdgcn_mfma_f32_16x16x32_bf16(
                        af[kk][m], bfr[kk][n], acc[m][n], 0, 0, 0);
        __builtin_amdgcn_s_setprio(0);
    }

    // Epilogue. D frag: col = lane&15, row = (lane>>4)*4 + reg  [verified map]
#pragma unroll
    for (int m = 0; m < 4; ++m) {
        int row = row0 + wr * 64 + m * 16 + lz * 4;
#pragma unroll
        for (int n = 0; n < 4; ++n) {
            int col = col0 + wc * 64 + n * 16 + lx;
            float bb = (ks == 0) ? bias[col] : 0.f;
            if (isV) {
#pragma unroll
                for (int r = 0; r < 4; ++r)
                    atomicAdd(&C[(size_t)(row + r) * N + col],
                              acc[m][n][r] + bb);
            } else {
#pragma unroll
                for (int r = 0; r < 4; ++r)
                    C[(size_t)(row + r) * N + col] = acc[m][n][r] + bb;
            }
        }
    }
}

// ---------------------------------------------------------------------------
extern "C" void kernel_launch(void* const* d_in, const int* in_sizes, int n_in,
                              void* d_out, int out_size, void* d_ws, size_t ws_size,
                              hipStream_t stream) {
    const float* vision   = (const float*)d_in[0];   // [2048, 4096]
    const float* language = (const float*)d_in[1];   // [2048, 20, 1024]
    const int*   plen     = (const int*)d_in[2];     // [2048]
    const float* Wv       = (const float*)d_in[3];   // [4096, 1024]
    const float* bv       = (const float*)d_in[4];   // [1024]
    const float* Wl       = (const float*)d_in[5];   // [1024, 1024]
    const float* bl       = (const float*)d_in[6];   // [1024]

    float* out      = (float*)d_out;
    float* lang_map = out;                        // output 0: [2048,1024]
    float* vis_map  = out + (size_t)M_ * H_;      // output 1: [2048,1024]

    char* ws = (char*)d_ws;
    ushort* pooled  = (ushort*)(ws);                   // 4 MB  [2048][1024]
    ushort* visionb = (ushort*)(ws + (4u  << 20));     // 16 MB [2048][4096]
    ushort* WvT     = (ushort*)(ws + (20u << 20));     // 8 MB  [1024][4096]
    ushort* WlT     = (ushort*)(ws + (28u << 20));     // 2 MB  [1024][1024]

    // prep: 2048 pool + 2048 cvt + 2048 WvT + 512 WlT + 512 zero = 7168
    hipLaunchKernelGGL(prep_kernel, dim3(7168), dim3(256), 0, stream,
                       language, plen, pooled, vision, visionb,
                       Wv, WvT, Wl, WlT, vis_map);
    // GEMM: 512 blocks x 256 threads (384 vision split-K + 128 language)
    hipLaunchKernelGGL(gemm_bt_dual, dim3(512), dim3(256), 0, stream,
                       visionb, WvT, bv, vis_map,
                       pooled,  WlT, bl, lang_map);
}